// Round 3
// baseline (1393.975 us; speedup 1.0000x reference)
//
#include <hip/hip_runtime.h>
#include <stdint.h>

typedef unsigned short ushort_t;
typedef short bf16x8 __attribute__((ext_vector_type(8)));
typedef float f32x4 __attribute__((ext_vector_type(4)));
typedef ushort_t us2 __attribute__((ext_vector_type(2)));
typedef ushort_t us4 __attribute__((ext_vector_type(4)));
typedef ushort_t us8 __attribute__((ext_vector_type(8)));

__device__ __forceinline__ float b2f(ushort_t u) {
    union { unsigned int i; float f; } v; v.i = ((unsigned int)u) << 16; return v.f;
}
__device__ __forceinline__ ushort_t f2b(float f) {
    union { float f; unsigned int i; } v; v.f = f;
    unsigned int r = v.i + 0x7fffu + ((v.i >> 16) & 1u);
    return (ushort_t)(r >> 16);
}

typedef __attribute__((address_space(3))) unsigned int lds_u32;
typedef __attribute__((address_space(1))) const unsigned int gbl_u32;

__device__ __forceinline__ void gload_lds16(const void* g, void* l) {
    __builtin_amdgcn_global_load_lds((gbl_u32*)g, (lds_u32*)l, 16, 0, 0);
}

// ---------------------------------------------------------------------------
// fp32 -> bf16 elementwise convert, 8 elems/thread.
// ---------------------------------------------------------------------------
__global__ void cvt_f32_bf16(const float* __restrict__ src, ushort_t* __restrict__ dst, int n8)
{
    const int i = blockIdx.x * 256 + threadIdx.x;
    if (i >= n8) return;
    f32x4 a = *(const f32x4*)&src[i * 8];
    f32x4 b = *(const f32x4*)&src[i * 8 + 4];
    us8 o;
#pragma unroll
    for (int j = 0; j < 4; j++) { o[j] = f2b(a[j]); o[j + 4] = f2b(b[j]); }
    *(us8*)&dst[i * 8] = o;
}

// ---------------------------------------------------------------------------
// C = A @ B^T + bias.  A:[M][K] bf16, B:[N][K] bf16, bias fp32.
// ---------------------------------------------------------------------------
template <bool OUT_F32>
__global__ __launch_bounds__(256, 2) void gemm_bt_bias(
    const ushort_t* __restrict__ A, const ushort_t* __restrict__ B,
    const float* __restrict__ bias, void* __restrict__ Cv,
    int M, int N, int K)
{
    __shared__ short As[128 * 32];
    __shared__ short Bs[128 * 32];
    const int t = threadIdx.x;
    const int lane = t & 63, w = t >> 6;
    const int qd = lane >> 4, ln = lane & 15;
    const int wm = w >> 1, wn = w & 1;
    const int m0 = blockIdx.y * 128, n0 = blockIdx.x * 128;

    f32x4 acc[4][4];
#pragma unroll
    for (int i = 0; i < 4; i++)
#pragma unroll
        for (int j = 0; j < 4; j++) acc[i][j] = (f32x4){0.f, 0.f, 0.f, 0.f};

    const int rowA = t >> 2, c16 = t & 3;
    const ushort_t* gA  = A + (size_t)(m0 + rowA) * K + c16 * 8;
    const ushort_t* gA2 = A + (size_t)(m0 + 64 + rowA) * K + c16 * 8;
    const ushort_t* gB  = B + (size_t)(n0 + rowA) * K + c16 * 8;
    const ushort_t* gB2 = B + (size_t)(n0 + 64 + rowA) * K + c16 * 8;
    short* lA  = &As[t * 8];
    short* lA2 = &As[(t + 256) * 8];
    short* lB  = &Bs[t * 8];
    short* lB2 = &Bs[(t + 256) * 8];

    for (int k0 = 0; k0 < K; k0 += 32) {
        __syncthreads();
        gload_lds16(gA + k0, lA);
        gload_lds16(gA2 + k0, lA2);
        gload_lds16(gB + k0, lB);
        gload_lds16(gB2 + k0, lB2);
        __syncthreads();

        bf16x8 af[4], bfv[4];
#pragma unroll
        for (int i = 0; i < 4; i++)
            af[i] = *(const bf16x8*)&As[(wm * 64 + i * 16 + ln) * 32 + qd * 8];
#pragma unroll
        for (int j = 0; j < 4; j++)
            bfv[j] = *(const bf16x8*)&Bs[(wn * 64 + j * 16 + ln) * 32 + qd * 8];
#pragma unroll
        for (int i = 0; i < 4; i++)
#pragma unroll
            for (int j = 0; j < 4; j++)
                acc[i][j] = __builtin_amdgcn_mfma_f32_16x16x32_bf16(
                    af[i], bfv[j], acc[i][j], 0, 0, 0);
    }

#pragma unroll
    for (int j = 0; j < 4; j++) {
        const int col = n0 + wn * 64 + j * 16 + ln;
        const float bv = bias[col];
#pragma unroll
        for (int i = 0; i < 4; i++) {
#pragma unroll
            for (int r = 0; r < 4; r++) {
                const int row = m0 + wm * 64 + i * 16 + qd * 4 + r;
                const float val = acc[i][j][r] + bv;
                if (OUT_F32) ((float*)Cv)[(size_t)row * N + col] = val;
                else         ((ushort_t*)Cv)[(size_t)row * N + col] = f2b(val);
            }
        }
    }
}

// ---------------------------------------------------------------------------
// RoPE for Q,K.  qkv(bf16):[8192][3456], cos/sin fp32 [8192][72]
// -> q_buf/k_buf bf16 [128 nh][1024 l][96] (cols 72..95 zero).
// ---------------------------------------------------------------------------
__global__ void rope_qk(const ushort_t* __restrict__ qkv,
                        const float* __restrict__ cosb,
                        const float* __restrict__ sinb,
                        ushort_t* __restrict__ qb, ushort_t* __restrict__ kb)
{
    const int idx = blockIdx.x * 256 + threadIdx.x;   // < 8192*144
    const int d0c = idx % 9;
    const int h = (idx / 9) & 15;
    const int s = idx / 144;
    const int d0 = d0c * 4;
    const int n = s >> 10, l = s & 1023;
    const size_t src = (size_t)s * 3456 + h * 72;
    const size_t dstrow = ((size_t)(n * 16 + h) * 1024 + l) * 96;

    f32x4 c1 = *(const f32x4*)&cosb[s * 72 + d0];
    f32x4 c2 = *(const f32x4*)&cosb[s * 72 + d0 + 36];
    f32x4 s1 = *(const f32x4*)&sinb[s * 72 + d0];
    f32x4 s2 = *(const f32x4*)&sinb[s * 72 + d0 + 36];

    {   // Q
        us4 x1 = *(const us4*)&qkv[src + d0];
        us4 x2 = *(const us4*)&qkv[src + d0 + 36];
        us4 o1, o2;
#pragma unroll
        for (int j = 0; j < 4; j++) {
            float a = b2f(x1[j]), b = b2f(x2[j]);
            o1[j] = f2b(a * c1[j] - b * s1[j]);
            o2[j] = f2b(b * c2[j] + a * s2[j]);
        }
        *(us4*)&qb[dstrow + d0] = o1;
        *(us4*)&qb[dstrow + d0 + 36] = o2;
    }
    {   // K
        us4 x1 = *(const us4*)&qkv[src + 1152 + d0];
        us4 x2 = *(const us4*)&qkv[src + 1152 + d0 + 36];
        us4 o1, o2;
#pragma unroll
        for (int j = 0; j < 4; j++) {
            float a = b2f(x1[j]), b = b2f(x2[j]);
            o1[j] = f2b(a * c1[j] - b * s1[j]);
            o2[j] = f2b(b * c2[j] + a * s2[j]);
        }
        *(us4*)&kb[dstrow + d0] = o1;
        *(us4*)&kb[dstrow + d0 + 36] = o2;
    }
    if (d0c < 6) {   // zero pad cols 72..95
        us4 z = (us4){0, 0, 0, 0};
        *(us4*)&qb[dstrow + 72 + d0c * 4] = z;
        *(us4*)&kb[dstrow + 72 + d0c * 4] = z;
    }
}

// ---------------------------------------------------------------------------
// V transpose: qkv(bf16)[s][2304+h*72+d] -> Vt [128 nh][80 d][1024 kv]
// (rows d=72..79 zero).  One block per (nh, 64-kv tile), LDS transpose.
// ---------------------------------------------------------------------------
__global__ void v_transpose(const ushort_t* __restrict__ qkv, ushort_t* __restrict__ vt)
{
    __shared__ short T[64 * 80];   // [kv-row][d], stride 80 (16B-aligned rows)
    const int t = threadIdx.x;
    const int nh = blockIdx.x >> 4, kvb = blockIdx.x & 15;
    const int h = nh & 15, n = nh >> 4;
    const int s0 = n * 1024 + kvb * 64;

    // load 64 rows x 72 d (9 us8 chunks per row)
#pragma unroll
    for (int i = 0; i < 3; i++) {
        int c = t + i * 256;
        if (c < 576) {
            int row = c / 9, off = (c % 9) * 8;
            *(us8*)&T[row * 80 + off] =
                *(const us8*)&qkv[(size_t)(s0 + row) * 3456 + 2304 + h * 72 + off];
        }
    }
    __syncthreads();

    // write 80 d-rows x 64 kv (8 us8 chunks per row)
#pragma unroll
    for (int i = 0; i < 3; i++) {
        int c = t + i * 256;
        if (c < 640) {
            int d = c >> 3, kc = c & 7;
            us8 o;
            if (d < 72) {
#pragma unroll
                for (int j = 0; j < 8; j++) o[j] = (ushort_t)T[(kc * 8 + j) * 80 + d];
            } else {
                o = (us8){0, 0, 0, 0, 0, 0, 0, 0};
            }
            *(us8*)&vt[((size_t)nh * 80 + d) * 1024 + kvb * 64 + kc * 8] = o;
        }
    }
}

// ---------------------------------------------------------------------------
// Flash attention per (nh, q-tile of 128).  BKV=64, online softmax.
// V held transposed: Vt[nh][80 d][1024 kv] -> PV B-frags are ds_read_b128.
// K/V global loads double-buffered in registers (prefetch next kv tile).
// ---------------------------------------------------------------------------
__global__ __launch_bounds__(256, 2) void flash_attn(
    const ushort_t* __restrict__ qb, const ushort_t* __restrict__ kb,
    const ushort_t* __restrict__ vt, ushort_t* __restrict__ ob)
{
    __shared__ short Qs[128 * 104];   // 26624 B
    __shared__ short Ks[64 * 104];    // 13312 B
    __shared__ short VtS[80 * 72];    // 11520 B  [d][kv], stride 72
    __shared__ short Ps[4][32 * 72];  // 18432 B  total 69888 B -> 2 blocks/CU

    const int t = threadIdx.x;
    const int lane = t & 63, w = t >> 6;
    const int qd = lane >> 4, ln = lane & 15;
    const int nh = blockIdx.x >> 3, qt = blockIdx.x & 7;
    const int q0 = qt * 128;
    const int h = nh & 15, n = nh >> 4;
    const float scale = 0.11785113019775793f;   // 72^-0.5

    // K staging map: c = t + i*256 (exactly 768 chunks): row=c/12, off=(c%12)*8
    const int krow[3] = { (t) / 12, (t + 256) / 12, (t + 512) / 12 };
    const int koff[3] = { (t % 12) * 8, ((t + 256) % 12) * 8, ((t + 512) % 12) * 8 };
    // V staging map: c < 640: d=c>>3, kc=c&7
    const int vd[3] = { t >> 3, (t + 256) >> 3, (t + 512) >> 3 };
    const int vkc[3] = { (t & 7) * 8, ((t + 256) & 7) * 8, ((t + 512) & 7) * 8 };

    const ushort_t* kbase = kb + (size_t)nh * 1024 * 96;
    const ushort_t* vbase = vt + (size_t)nh * 80 * 1024;

    {   // stage Q tile: 128 rows x 96
        const ushort_t* src = qb + ((size_t)nh * 1024 + q0) * 96;
#pragma unroll
        for (int i = 0; i < 6; i++) {
            int c = t + i * 256;
            int row = c / 12, off = (c % 12) * 8;
            *(us8*)&Qs[row * 104 + off] = *(const us8*)&src[row * 96 + off];
        }
    }

    us8 kreg[2][3], vreg[2][3];
    // prefetch kv tile 0 into buffer 0
#pragma unroll
    for (int i = 0; i < 3; i++) {
        kreg[0][i] = *(const us8*)&kbase[(size_t)krow[i] * 96 + koff[i]];
        if (t + i * 256 < 640)
            vreg[0][i] = *(const us8*)&vbase[(size_t)vd[i] * 1024 + vkc[i]];
    }

    float m_st[2][4], l_st[2][4];
    f32x4 acc_o[2][5];
#pragma unroll
    for (int im = 0; im < 2; im++) {
#pragma unroll
        for (int r = 0; r < 4; r++) { m_st[im][r] = -INFINITY; l_st[im][r] = 0.f; }
#pragma unroll
        for (int jn = 0; jn < 5; jn++) acc_o[im][jn] = (f32x4){0.f, 0.f, 0.f, 0.f};
    }

    for (int it = 0; it < 16; it++) {
        const int cur = it & 1;
        __syncthreads();   // prev-iter LDS consumers done (also covers Q stage)
        // store staged K/V regs to LDS
#pragma unroll
        for (int i = 0; i < 3; i++) {
            *(us8*)&Ks[krow[i] * 104 + koff[i]] = kreg[cur][i];
            if (t + i * 256 < 640)
                *(us8*)&VtS[vd[i] * 72 + vkc[i]] = vreg[cur][i];
        }
        // prefetch next kv tile into other buffer
        if (it < 15) {
            const int kv1 = (it + 1) * 64;
#pragma unroll
            for (int i = 0; i < 3; i++) {
                kreg[cur ^ 1][i] = *(const us8*)&kbase[(size_t)(kv1 + krow[i]) * 96 + koff[i]];
                if (t + i * 256 < 640)
                    vreg[cur ^ 1][i] = *(const us8*)&vbase[(size_t)vd[i] * 1024 + kv1 + vkc[i]];
            }
        }
        __syncthreads();

        // ---- Q K^T ----
        f32x4 sc[2][4];
#pragma unroll
        for (int im = 0; im < 2; im++)
#pragma unroll
            for (int jk = 0; jk < 4; jk++) sc[im][jk] = (f32x4){0.f, 0.f, 0.f, 0.f};
#pragma unroll
        for (int ks = 0; ks < 3; ks++) {
            bf16x8 a0 = *(const bf16x8*)&Qs[(w * 32 + ln) * 104 + ks * 32 + qd * 8];
            bf16x8 a1 = *(const bf16x8*)&Qs[(w * 32 + 16 + ln) * 104 + ks * 32 + qd * 8];
#pragma unroll
            for (int jk = 0; jk < 4; jk++) {
                bf16x8 bfr = *(const bf16x8*)&Ks[(jk * 16 + ln) * 104 + ks * 32 + qd * 8];
                sc[0][jk] = __builtin_amdgcn_mfma_f32_16x16x32_bf16(a0, bfr, sc[0][jk], 0, 0, 0);
                sc[1][jk] = __builtin_amdgcn_mfma_f32_16x16x32_bf16(a1, bfr, sc[1][jk], 0, 0, 0);
            }
        }

        // ---- online softmax ----
#pragma unroll
        for (int im = 0; im < 2; im++) {
#pragma unroll
            for (int r = 0; r < 4; r++) {
                float v0 = sc[im][0][r] * scale, v1 = sc[im][1][r] * scale;
                float v2 = sc[im][2][r] * scale, v3 = sc[im][3][r] * scale;
                float mt = fmaxf(fmaxf(v0, v1), fmaxf(v2, v3));
                mt = fmaxf(mt, __shfl_xor(mt, 1));
                mt = fmaxf(mt, __shfl_xor(mt, 2));
                mt = fmaxf(mt, __shfl_xor(mt, 4));
                mt = fmaxf(mt, __shfl_xor(mt, 8));
                float mo = m_st[im][r];
                float mn = fmaxf(mo, mt);
                float al = __expf(mo - mn);
                float p0 = __expf(v0 - mn), p1 = __expf(v1 - mn);
                float p2 = __expf(v2 - mn), p3 = __expf(v3 - mn);
                float rs = p0 + p1 + p2 + p3;
                rs += __shfl_xor(rs, 1);
                rs += __shfl_xor(rs, 2);
                rs += __shfl_xor(rs, 4);
                rs += __shfl_xor(rs, 8);
                m_st[im][r] = mn;
                l_st[im][r] = l_st[im][r] * al + rs;
#pragma unroll
                for (int jn = 0; jn < 5; jn++) acc_o[im][jn][r] *= al;
                short* pd = &Ps[w][(im * 16 + qd * 4 + r) * 72 + ln];
                pd[0]  = (short)f2b(p0);
                pd[16] = (short)f2b(p1);
                pd[32] = (short)f2b(p2);
                pd[48] = (short)f2b(p3);
            }
        }

        // ---- P V ----  (Ps wave-private; Vt B-frags are contiguous b128)
#pragma unroll
        for (int ks = 0; ks < 2; ks++) {
            bf16x8 p0f = *(const bf16x8*)&Ps[w][(ln) * 72 + ks * 32 + qd * 8];
            bf16x8 p1f = *(const bf16x8*)&Ps[w][(16 + ln) * 72 + ks * 32 + qd * 8];
#pragma unroll
            for (int jn = 0; jn < 5; jn++) {
                bf16x8 vf = *(const bf16x8*)&VtS[(jn * 16 + ln) * 72 + ks * 32 + qd * 8];
                acc_o[0][jn] = __builtin_amdgcn_mfma_f32_16x16x32_bf16(p0f, vf, acc_o[0][jn], 0, 0, 0);
                acc_o[1][jn] = __builtin_amdgcn_mfma_f32_16x16x32_bf16(p1f, vf, acc_o[1][jn], 0, 0, 0);
            }
        }
    }

    // ---- epilogue ----
    const size_t obase = ((size_t)(n * 1024 + q0)) * 1152 + h * 72;
#pragma unroll
    for (int im = 0; im < 2; im++) {
#pragma unroll
        for (int r = 0; r < 4; r++) {
            const int rowl = w * 32 + im * 16 + qd * 4 + r;
            const float inv = 1.0f / l_st[im][r];
#pragma unroll
            for (int jn = 0; jn < 5; jn++) {
                const int d = jn * 16 + ln;
                if (d < 72)
                    ob[obase + (size_t)rowl * 1152 + d] = f2b(acc_o[im][jn][r] * inv);
            }
        }
    }
}

// ---------------------------------------------------------------------------
extern "C" void kernel_launch(void* const* d_in, const int* in_sizes, int n_in,
                              void* d_out, int out_size, void* d_ws, size_t ws_size,
                              hipStream_t stream)
{
    const float* hs     = (const float*)d_in[0];
    const float* cosb   = (const float*)d_in[1];
    const float* sinb   = (const float*)d_in[2];
    const float* qkv_w  = (const float*)d_in[3];
    const float* qkv_b  = (const float*)d_in[4];
    const float* proj_w = (const float*)d_in[5];
    const float* proj_b = (const float*)d_in[6];

    char* ws = (char*)d_ws;
    // hidden_bf16 (dead after gemm1) aliases attn (written by flash_attn)
    ushort_t* hs_bf   = (ushort_t*)(ws);                //  8192*1152*2 = 18,874,368
    ushort_t* attn    = (ushort_t*)(ws);                //  aliases hs_bf
    ushort_t* qkvw_bf = (ushort_t*)(ws + 18874368);     //  3456*1152*2 =  7,962,624
    ushort_t* projw_bf= (ushort_t*)(ws + 26836992);     //  1152*1152*2 =  2,654,208
    ushort_t* qkv_tmp = (ushort_t*)(ws + 29491200);     //  8192*3456*2 = 56,623,104
    ushort_t* q_buf   = (ushort_t*)(ws + 86114304);     //  128*1024*96*2 = 25,165,824
    ushort_t* k_buf   = (ushort_t*)(ws + 111280128);    //  25,165,824
    ushort_t* v_t     = (ushort_t*)(ws + 136445952);    //  128*80*1024*2 = 20,971,520
    float*    out     = (float*)d_out;                  //  total ws: 157,417,472 B

    cvt_f32_bf16<<<4608, 256, 0, stream>>>(hs, hs_bf, 9437184 / 8);
    cvt_f32_bf16<<<1944, 256, 0, stream>>>(qkv_w, qkvw_bf, 3981312 / 8);
    cvt_f32_bf16<<<648, 256, 0, stream>>>(proj_w, projw_bf, 1327104 / 8);

    gemm_bt_bias<false><<<dim3(27, 64), 256, 0, stream>>>(hs_bf, qkvw_bf, qkv_b, qkv_tmp, 8192, 3456, 1152);
    rope_qk<<<4608, 256, 0, stream>>>(qkv_tmp, cosb, sinb, q_buf, k_buf);
    v_transpose<<<2048, 256, 0, stream>>>(qkv_tmp, v_t);
    flash_attn<<<1024, 256, 0, stream>>>(q_buf, k_buf, v_t, attn);
    gemm_bt_bias<true><<<dim3(9, 64), 256, 0, stream>>>(attn, projw_bf, proj_b, out, 8192, 1152, 1152);
}

// Round 4
// 419.692 us; speedup vs baseline: 3.3214x; 3.3214x over previous
//
#include <hip/hip_runtime.h>
#include <stdint.h>

typedef unsigned short ushort_t;
typedef short bf16x8 __attribute__((ext_vector_type(8)));
typedef float f32x4 __attribute__((ext_vector_type(4)));
typedef ushort_t us2 __attribute__((ext_vector_type(2)));
typedef ushort_t us4 __attribute__((ext_vector_type(4)));
typedef ushort_t us8 __attribute__((ext_vector_type(8)));

__device__ __forceinline__ float b2f(ushort_t u) {
    union { unsigned int i; float f; } v; v.i = ((unsigned int)u) << 16; return v.f;
}
__device__ __forceinline__ ushort_t f2b(float f) {
    union { float f; unsigned int i; } v; v.f = f;
    unsigned int r = v.i + 0x7fffu + ((v.i >> 16) & 1u);
    return (ushort_t)(r >> 16);
}

typedef __attribute__((address_space(3))) unsigned int lds_u32;
typedef __attribute__((address_space(1))) const unsigned int gbl_u32;

__device__ __forceinline__ void gload_lds16(const void* g, void* l) {
    __builtin_amdgcn_global_load_lds((gbl_u32*)g, (lds_u32*)l, 16, 0, 0);
}

// ---------------------------------------------------------------------------
// fp32 -> bf16 elementwise convert, 8 elems/thread.
// ---------------------------------------------------------------------------
__global__ void cvt_f32_bf16(const float* __restrict__ src, ushort_t* __restrict__ dst, int n8)
{
    const int i = blockIdx.x * 256 + threadIdx.x;
    if (i >= n8) return;
    f32x4 a = *(const f32x4*)&src[i * 8];
    f32x4 b = *(const f32x4*)&src[i * 8 + 4];
    us8 o;
#pragma unroll
    for (int j = 0; j < 4; j++) { o[j] = f2b(a[j]); o[j + 4] = f2b(b[j]); }
    *(us8*)&dst[i * 8] = o;
}

// ---------------------------------------------------------------------------
// C = A @ B^T + bias.  A:[M][K] bf16, B:[N][K] bf16, bias fp32.
// ---------------------------------------------------------------------------
template <bool OUT_F32>
__global__ __launch_bounds__(256, 2) void gemm_bt_bias(
    const ushort_t* __restrict__ A, const ushort_t* __restrict__ B,
    const float* __restrict__ bias, void* __restrict__ Cv,
    int M, int N, int K)
{
    __shared__ short As[128 * 32];
    __shared__ short Bs[128 * 32];
    const int t = threadIdx.x;
    const int lane = t & 63, w = t >> 6;
    const int qd = lane >> 4, ln = lane & 15;
    const int wm = w >> 1, wn = w & 1;
    const int m0 = blockIdx.y * 128, n0 = blockIdx.x * 128;

    f32x4 acc[4][4];
#pragma unroll
    for (int i = 0; i < 4; i++)
#pragma unroll
        for (int j = 0; j < 4; j++) acc[i][j] = (f32x4){0.f, 0.f, 0.f, 0.f};

    const int rowA = t >> 2, c16 = t & 3;
    const ushort_t* gA  = A + (size_t)(m0 + rowA) * K + c16 * 8;
    const ushort_t* gA2 = A + (size_t)(m0 + 64 + rowA) * K + c16 * 8;
    const ushort_t* gB  = B + (size_t)(n0 + rowA) * K + c16 * 8;
    const ushort_t* gB2 = B + (size_t)(n0 + 64 + rowA) * K + c16 * 8;
    short* lA  = &As[t * 8];
    short* lA2 = &As[(t + 256) * 8];
    short* lB  = &Bs[t * 8];
    short* lB2 = &Bs[(t + 256) * 8];

    for (int k0 = 0; k0 < K; k0 += 32) {
        __syncthreads();
        gload_lds16(gA + k0, lA);
        gload_lds16(gA2 + k0, lA2);
        gload_lds16(gB + k0, lB);
        gload_lds16(gB2 + k0, lB2);
        __syncthreads();

        bf16x8 af[4], bfv[4];
#pragma unroll
        for (int i = 0; i < 4; i++)
            af[i] = *(const bf16x8*)&As[(wm * 64 + i * 16 + ln) * 32 + qd * 8];
#pragma unroll
        for (int j = 0; j < 4; j++)
            bfv[j] = *(const bf16x8*)&Bs[(wn * 64 + j * 16 + ln) * 32 + qd * 8];
#pragma unroll
        for (int i = 0; i < 4; i++)
#pragma unroll
            for (int j = 0; j < 4; j++)
                acc[i][j] = __builtin_amdgcn_mfma_f32_16x16x32_bf16(
                    af[i], bfv[j], acc[i][j], 0, 0, 0);
    }

#pragma unroll
    for (int j = 0; j < 4; j++) {
        const int col = n0 + wn * 64 + j * 16 + ln;
        const float bv = bias[col];
#pragma unroll
        for (int i = 0; i < 4; i++) {
#pragma unroll
            for (int r = 0; r < 4; r++) {
                const int row = m0 + wm * 64 + i * 16 + qd * 4 + r;
                const float val = acc[i][j][r] + bv;
                if (OUT_F32) ((float*)Cv)[(size_t)row * N + col] = val;
                else         ((ushort_t*)Cv)[(size_t)row * N + col] = f2b(val);
            }
        }
    }
}

// ---------------------------------------------------------------------------
// RoPE for Q,K.  qkv(bf16):[8192][3456], cos/sin fp32 [8192][72]
// -> q_buf/k_buf bf16 [128 nh][1024 l][96] (cols 72..95 zero).
// ---------------------------------------------------------------------------
__global__ void rope_qk(const ushort_t* __restrict__ qkv,
                        const float* __restrict__ cosb,
                        const float* __restrict__ sinb,
                        ushort_t* __restrict__ qb, ushort_t* __restrict__ kb)
{
    const int idx = blockIdx.x * 256 + threadIdx.x;   // < 8192*144
    const int d0c = idx % 9;
    const int h = (idx / 9) & 15;
    const int s = idx / 144;
    const int d0 = d0c * 4;
    const int n = s >> 10, l = s & 1023;
    const size_t src = (size_t)s * 3456 + h * 72;
    const size_t dstrow = ((size_t)(n * 16 + h) * 1024 + l) * 96;

    f32x4 c1 = *(const f32x4*)&cosb[s * 72 + d0];
    f32x4 c2 = *(const f32x4*)&cosb[s * 72 + d0 + 36];
    f32x4 s1 = *(const f32x4*)&sinb[s * 72 + d0];
    f32x4 s2 = *(const f32x4*)&sinb[s * 72 + d0 + 36];

    {   // Q
        us4 x1 = *(const us4*)&qkv[src + d0];
        us4 x2 = *(const us4*)&qkv[src + d0 + 36];
        us4 o1, o2;
#pragma unroll
        for (int j = 0; j < 4; j++) {
            float a = b2f(x1[j]), b = b2f(x2[j]);
            o1[j] = f2b(a * c1[j] - b * s1[j]);
            o2[j] = f2b(b * c2[j] + a * s2[j]);
        }
        *(us4*)&qb[dstrow + d0] = o1;
        *(us4*)&qb[dstrow + d0 + 36] = o2;
    }
    {   // K
        us4 x1 = *(const us4*)&qkv[src + 1152 + d0];
        us4 x2 = *(const us4*)&qkv[src + 1152 + d0 + 36];
        us4 o1, o2;
#pragma unroll
        for (int j = 0; j < 4; j++) {
            float a = b2f(x1[j]), b = b2f(x2[j]);
            o1[j] = f2b(a * c1[j] - b * s1[j]);
            o2[j] = f2b(b * c2[j] + a * s2[j]);
        }
        *(us4*)&kb[dstrow + d0] = o1;
        *(us4*)&kb[dstrow + d0 + 36] = o2;
    }
    if (d0c < 6) {   // zero pad cols 72..95
        us4 z = (us4){0, 0, 0, 0};
        *(us4*)&qb[dstrow + 72 + d0c * 4] = z;
        *(us4*)&kb[dstrow + 72 + d0c * 4] = z;
    }
}

// ---------------------------------------------------------------------------
// V transpose: qkv(bf16)[s][2304+h*72+d] -> Vt [128 nh][80 d][1024 kv]
// (rows d=72..79 zero).  One block per (nh, 64-kv tile), LDS transpose.
// ---------------------------------------------------------------------------
__global__ void v_transpose(const ushort_t* __restrict__ qkv, ushort_t* __restrict__ vt)
{
    __shared__ short T[64 * 80];   // [kv-row][d], stride 80 (16B-aligned rows)
    const int t = threadIdx.x;
    const int nh = blockIdx.x >> 4, kvb = blockIdx.x & 15;
    const int h = nh & 15, n = nh >> 4;
    const int s0 = n * 1024 + kvb * 64;

    // load 64 rows x 72 d (9 us8 chunks per row)
#pragma unroll
    for (int i = 0; i < 3; i++) {
        int c = t + i * 256;
        if (c < 576) {
            int row = c / 9, off = (c % 9) * 8;
            *(us8*)&T[row * 80 + off] =
                *(const us8*)&qkv[(size_t)(s0 + row) * 3456 + 2304 + h * 72 + off];
        }
    }
    __syncthreads();

    // write 80 d-rows x 64 kv (8 us8 chunks per row)
#pragma unroll
    for (int i = 0; i < 3; i++) {
        int c = t + i * 256;
        if (c < 640) {
            int d = c >> 3, kc = c & 7;
            us8 o;
            if (d < 72) {
#pragma unroll
                for (int j = 0; j < 8; j++) o[j] = (ushort_t)T[(kc * 8 + j) * 80 + d];
            } else {
                o = (us8){0, 0, 0, 0, 0, 0, 0, 0};
            }
            *(us8*)&vt[((size_t)nh * 80 + d) * 1024 + kvb * 64 + kc * 8] = o;
        }
    }
}

// ---------------------------------------------------------------------------
// Flash attention per (nh, q-tile of 128).  BKV=64, online softmax.
// Q/K staged via global_load_lds DMA (stride 96, lane-contiguous).
// V transposed in global (Vt[nh][80][1024]); single STATIC register buffer
// vr[3] prefetches next tile's V (no dynamic register indexing!).
// ---------------------------------------------------------------------------
__global__ __launch_bounds__(256, 2) void flash_attn(
    const ushort_t* __restrict__ qb, const ushort_t* __restrict__ kb,
    const ushort_t* __restrict__ vt, ushort_t* __restrict__ ob)
{
    __shared__ short Qs[128 * 96];    // 24576 B
    __shared__ short Ks[64 * 96];     // 12288 B
    __shared__ short VtS[80 * 72];    // 11520 B  [d][kv], stride 72
    __shared__ short Ps[4][32 * 72];  // 18432 B  -> total 66816 B, 2 blocks/CU

    const int t = threadIdx.x;
    const int lane = t & 63, w = t >> 6;
    const int qd = lane >> 4, ln = lane & 15;
    const int nh = blockIdx.x >> 3, qt = blockIdx.x & 7;
    const int q0 = qt * 128;
    const int h = nh & 15, n = nh >> 4;
    const float scale = 0.11785113019775793f;   // 72^-0.5

    const ushort_t* kbase = kb + (size_t)nh * 1024 * 96;
    const ushort_t* vbase = vt + (size_t)nh * 80 * 1024;

    {   // stage Q via DMA: 1536 16B chunks, LDS offset == global offset
        const ushort_t* src = qb + ((size_t)nh * 1024 + q0) * 96;
#pragma unroll
        for (int i = 0; i < 6; i++)
            gload_lds16(src + (t + i * 256) * 8, &Qs[(t + i * 256) * 8]);
    }

    // V staging map (640 chunks): chunk c -> d=c>>3, kv-chunk=(c&7)*8
    const int vd0 = t >> 3;            // c = t       : d 0..31
    const int vkc0 = (t & 7) * 8;
    const int vd2 = 64 + (t >> 3);     // c = t+512   : d 64..79 (t<128)
    us8 vr0, vr1, vr2;
    vr0 = *(const us8*)&vbase[(size_t)vd0 * 1024 + vkc0];
    vr1 = *(const us8*)&vbase[(size_t)(vd0 + 32) * 1024 + vkc0];
    if (t < 128) vr2 = *(const us8*)&vbase[(size_t)vd2 * 1024 + vkc0];

    float m_st[2][4], l_st[2][4];
    f32x4 acc_o[2][5];
#pragma unroll
    for (int im = 0; im < 2; im++) {
#pragma unroll
        for (int r = 0; r < 4; r++) { m_st[im][r] = -INFINITY; l_st[im][r] = 0.f; }
#pragma unroll
        for (int jn = 0; jn < 5; jn++) acc_o[im][jn] = (f32x4){0.f, 0.f, 0.f, 0.f};
    }

    for (int it = 0; it < 16; it++) {
        __syncthreads();   // prior compute done reading Ks/VtS (and Q DMA ordering)
        {   // K tile via DMA: 768 chunks
            const ushort_t* ksrc = kbase + (size_t)it * 64 * 96;
#pragma unroll
            for (int i = 0; i < 3; i++)
                gload_lds16(ksrc + (t + i * 256) * 8, &Ks[(t + i * 256) * 8]);
        }
        // store the prefetched V tile (vmcnt wait on vr* inserted by compiler)
        *(us8*)&VtS[vd0 * 72 + vkc0] = vr0;
        *(us8*)&VtS[(vd0 + 32) * 72 + vkc0] = vr1;
        if (t < 128) *(us8*)&VtS[vd2 * 72 + vkc0] = vr2;
        // issue next tile's V loads (consumed next iteration)
        if (it < 15) {
            const ushort_t* vsrc = vbase + (it + 1) * 64;
            vr0 = *(const us8*)&vsrc[(size_t)vd0 * 1024 + vkc0];
            vr1 = *(const us8*)&vsrc[(size_t)(vd0 + 32) * 1024 + vkc0];
            if (t < 128) vr2 = *(const us8*)&vsrc[(size_t)vd2 * 1024 + vkc0];
        }
        __syncthreads();   // drains K DMA

        // ---- Q K^T ----
        f32x4 sc[2][4];
#pragma unroll
        for (int im = 0; im < 2; im++)
#pragma unroll
            for (int jk = 0; jk < 4; jk++) sc[im][jk] = (f32x4){0.f, 0.f, 0.f, 0.f};
#pragma unroll
        for (int ks = 0; ks < 3; ks++) {
            bf16x8 a0 = *(const bf16x8*)&Qs[(w * 32 + ln) * 96 + ks * 32 + qd * 8];
            bf16x8 a1 = *(const bf16x8*)&Qs[(w * 32 + 16 + ln) * 96 + ks * 32 + qd * 8];
#pragma unroll
            for (int jk = 0; jk < 4; jk++) {
                bf16x8 bfr = *(const bf16x8*)&Ks[(jk * 16 + ln) * 96 + ks * 32 + qd * 8];
                sc[0][jk] = __builtin_amdgcn_mfma_f32_16x16x32_bf16(a0, bfr, sc[0][jk], 0, 0, 0);
                sc[1][jk] = __builtin_amdgcn_mfma_f32_16x16x32_bf16(a1, bfr, sc[1][jk], 0, 0, 0);
            }
        }

        // ---- online softmax ----
#pragma unroll
        for (int im = 0; im < 2; im++) {
#pragma unroll
            for (int r = 0; r < 4; r++) {
                float v0 = sc[im][0][r] * scale, v1 = sc[im][1][r] * scale;
                float v2 = sc[im][2][r] * scale, v3 = sc[im][3][r] * scale;
                float mt = fmaxf(fmaxf(v0, v1), fmaxf(v2, v3));
                mt = fmaxf(mt, __shfl_xor(mt, 1));
                mt = fmaxf(mt, __shfl_xor(mt, 2));
                mt = fmaxf(mt, __shfl_xor(mt, 4));
                mt = fmaxf(mt, __shfl_xor(mt, 8));
                float mo = m_st[im][r];
                float mn = fmaxf(mo, mt);
                float al = __expf(mo - mn);
                float p0 = __expf(v0 - mn), p1 = __expf(v1 - mn);
                float p2 = __expf(v2 - mn), p3 = __expf(v3 - mn);
                float rs = p0 + p1 + p2 + p3;
                rs += __shfl_xor(rs, 1);
                rs += __shfl_xor(rs, 2);
                rs += __shfl_xor(rs, 4);
                rs += __shfl_xor(rs, 8);
                m_st[im][r] = mn;
                l_st[im][r] = l_st[im][r] * al + rs;
#pragma unroll
                for (int jn = 0; jn < 5; jn++) acc_o[im][jn][r] *= al;
                short* pd = &Ps[w][(im * 16 + qd * 4 + r) * 72 + ln];
                pd[0]  = (short)f2b(p0);
                pd[16] = (short)f2b(p1);
                pd[32] = (short)f2b(p2);
                pd[48] = (short)f2b(p3);
            }
        }

        // ---- P V ----  (Ps wave-private; Vt B-frags contiguous b128)
#pragma unroll
        for (int ks = 0; ks < 2; ks++) {
            bf16x8 p0f = *(const bf16x8*)&Ps[w][(ln) * 72 + ks * 32 + qd * 8];
            bf16x8 p1f = *(const bf16x8*)&Ps[w][(16 + ln) * 72 + ks * 32 + qd * 8];
#pragma unroll
            for (int jn = 0; jn < 5; jn++) {
                bf16x8 vf = *(const bf16x8*)&VtS[(jn * 16 + ln) * 72 + ks * 32 + qd * 8];
                acc_o[0][jn] = __builtin_amdgcn_mfma_f32_16x16x32_bf16(p0f, vf, acc_o[0][jn], 0, 0, 0);
                acc_o[1][jn] = __builtin_amdgcn_mfma_f32_16x16x32_bf16(p1f, vf, acc_o[1][jn], 0, 0, 0);
            }
        }
    }

    // ---- epilogue ----
    const size_t obase = ((size_t)(n * 1024 + q0)) * 1152 + h * 72;
#pragma unroll
    for (int im = 0; im < 2; im++) {
#pragma unroll
        for (int r = 0; r < 4; r++) {
            const int rowl = w * 32 + im * 16 + qd * 4 + r;
            const float inv = 1.0f / l_st[im][r];
#pragma unroll
            for (int jn = 0; jn < 5; jn++) {
                const int d = jn * 16 + ln;
                if (d < 72)
                    ob[obase + (size_t)rowl * 1152 + d] = f2b(acc_o[im][jn][r] * inv);
            }
        }
    }
}

// ---------------------------------------------------------------------------
extern "C" void kernel_launch(void* const* d_in, const int* in_sizes, int n_in,
                              void* d_out, int out_size, void* d_ws, size_t ws_size,
                              hipStream_t stream)
{
    const float* hs     = (const float*)d_in[0];
    const float* cosb   = (const float*)d_in[1];
    const float* sinb   = (const float*)d_in[2];
    const float* qkv_w  = (const float*)d_in[3];
    const float* qkv_b  = (const float*)d_in[4];
    const float* proj_w = (const float*)d_in[5];
    const float* proj_b = (const float*)d_in[6];

    char* ws = (char*)d_ws;
    // hidden_bf16 (dead after gemm1) aliases attn (written by flash_attn)
    ushort_t* hs_bf   = (ushort_t*)(ws);                //  8192*1152*2 = 18,874,368
    ushort_t* attn    = (ushort_t*)(ws);                //  aliases hs_bf
    ushort_t* qkvw_bf = (ushort_t*)(ws + 18874368);     //  3456*1152*2 =  7,962,624
    ushort_t* projw_bf= (ushort_t*)(ws + 26836992);     //  1152*1152*2 =  2,654,208
    ushort_t* qkv_tmp = (ushort_t*)(ws + 29491200);     //  8192*3456*2 = 56,623,104
    ushort_t* q_buf   = (ushort_t*)(ws + 86114304);     //  128*1024*96*2 = 25,165,824
    ushort_t* k_buf   = (ushort_t*)(ws + 111280128);    //  25,165,824
    ushort_t* v_t     = (ushort_t*)(ws + 136445952);    //  128*80*1024*2 = 20,971,520
    float*    out     = (float*)d_out;                  //  total ws: 157,417,472 B

    cvt_f32_bf16<<<4608, 256, 0, stream>>>(hs, hs_bf, 9437184 / 8);
    cvt_f32_bf16<<<1944, 256, 0, stream>>>(qkv_w, qkvw_bf, 3981312 / 8);
    cvt_f32_bf16<<<648, 256, 0, stream>>>(proj_w, projw_bf, 1327104 / 8);

    gemm_bt_bias<false><<<dim3(27, 64), 256, 0, stream>>>(hs_bf, qkvw_bf, qkv_b, qkv_tmp, 8192, 3456, 1152);
    rope_qk<<<4608, 256, 0, stream>>>(qkv_tmp, cosb, sinb, q_buf, k_buf);
    v_transpose<<<2048, 256, 0, stream>>>(qkv_tmp, v_t);
    flash_attn<<<1024, 256, 0, stream>>>(q_buf, k_buf, v_t, attn);
    gemm_bt_bias<true><<<dim3(9, 64), 256, 0, stream>>>(attn, projw_bf, proj_b, out, 8192, 1152, 1152);
}